// Round 8
// baseline (356.039 us; speedup 1.0000x reference)
//
#include <hip/hip_runtime.h>
#include <math.h>

// SuperVoxel critical-component loss on MI355X.
// mean( (0.5 + 0.25*neg + 0.25*pos) * bce_loss )
// Run-based two-level CCL. Pipeline:
//  k_maskloss: read floats ONCE -> fg masks, run-start masks/prefixes/counts,
//              fp16 per-pixel loss, and the 0.5*sum(loss) base term.
//  k_strip:    16-row strips, all intra-strip unions+flags in 32KB LDS
//              (4 blocks/CU), 4-way sub-word task split, used-slots only.
//  k_bound:    global flag-carrying unions on the 63 strip seams per image.
//  k_compress: used-slots-only fold of root|flag into every run entry.
//  k_accumflag: adds 0.25*loss terms for runs whose root is flagged.

#define HH 1024
#define WW 1024
#define IMGPIX (HH * WW)
#define NB_TOTAL 16
#define FLAGBIT 0x40000000
#define IDXMASK 0x3FFFFFFF
#define NBLK 2048
#define NPART 2048
#define NTHR 256
#define WPR 16               // u64 mask words per row
#define RPR 512              // run slots per row (hard worst case)
#define SROWS 16             // rows per strip
#define STRIPS (HH / SROWS)  // 64 strips per image
#define SLOTS (SROWS * RPR)  // 8192 slots per strip (32KB LDS)
#define NTHR_S 512

typedef unsigned long long u64;

// ---------- global union-find (flag-aware) ----------
__device__ __forceinline__ int findRootG(const int* __restrict__ p, int i) {
    int r = i;
    int pr = p[r] & IDXMASK;
    while (pr != r) { r = pr; pr = p[r] & IDXMASK; }
    return r;
}

__device__ __forceinline__ void flagProp(int* p, int x) {
    while (true) {
        int r = findRootG(p, x);
        int old = atomicOr(&p[r], FLAGBIT);
        if ((old & IDXMASK) == r) return;  // was still a root
        x = old & IDXMASK;
    }
}

__device__ __forceinline__ void uniteGF(int* p, int a, int b) {
    int ra = findRootG(p, a), rb = findRootG(p, b);
    while (ra != rb) {
        if (ra < rb) { int t = ra; ra = rb; rb = t; }  // hook larger under smaller
        int e = p[ra];
        if ((e & IDXMASK) != ra) { ra = findRootG(p, e & IDXMASK); continue; }
        int prev = atomicCAS(&p[ra], e, rb);
        if (prev == e) {
            if (e & FLAGBIT) flagProp(p, rb);
            return;
        }
        ra = findRootG(p, prev & IDXMASK);
        rb = findRootG(p, rb);
    }
}

// ---------- LDS union-find ----------
__device__ __forceinline__ int findRootL(volatile int* lab, int i) {
    int r = i;
    int e = lab[r] & IDXMASK;
    while (e != r) { r = e; e = lab[r] & IDXMASK; }
    return r;
}

__device__ __forceinline__ void uniteL(int* lab, int a, int b) {
    volatile int* vl = lab;
    int ra = findRootL(vl, a), rb = findRootL(vl, b);
    while (ra != rb) {
        if (ra < rb) { int t = ra; ra = rb; rb = t; }
        int prev = atomicCAS(&lab[ra], ra, rb);
        if (prev == ra) return;
        ra = findRootL(vl, prev & IDXMASK);
        rb = findRootL(vl, rb);
    }
}

// index (within row) of the run containing bit b of this word; requires fg@b.
__device__ __forceinline__ int runIndexW(u64 starts, int b) {
    u64 below = (2ULL << b) - 1ULL;  // b=63 wraps to ~0ULL
    return (int)__popcll(starts & below) - 1;
}

__global__ void k_zero(double* __restrict__ part) {
    part[blockIdx.x * blockDim.x + threadIdx.x] = 0.0;
}

// Wave-per-row: read floats once; emit masks, run structure, fp16 loss, and
// the 0.5*sum(loss) base term into per-block partials.
__global__ void k_maskloss(const float* __restrict__ preds, const float* __restrict__ targets,
                           long gbase, int nrows,
                           u64* __restrict__ fT, u64* __restrict__ fP,
                           u64* __restrict__ sT, u64* __restrict__ sP,
                           int* __restrict__ prT, int* __restrict__ prP,
                           int* __restrict__ rcT, int* __restrict__ rcP,
                           _Float16* __restrict__ lossH, double* __restrict__ part) {
    int wid = threadIdx.x >> 6, lane = threadIdx.x & 63;
    double lsum = 0.0;
    for (int R = blockIdx.x * 4 + wid; R < nrows; R += gridDim.x * 4) {
        long pixbase = (long)R * WW;
        int cumT = 0, cumP = 0;
        u64 carryT = 0, carryP = 0;
        #pragma unroll 4
        for (int w = 0; w < WPR; ++w) {
            long g = gbase + pixbase + w * 64 + lane;
            float p = preds[g], t = targets[g];
            float loss = fmaxf(p, 0.0f) - p * t + log1pf(expf(-fabsf(p)));
            lossH[pixbase + w * 64 + lane] = (_Float16)loss;
            lsum += (double)loss;
            u64 bt = __ballot(t > 0.0f);
            u64 bp = __ballot(p > 0.5f);
            if (lane == 0) {
                int wi = R * WPR + w;
                fT[wi] = bt; fP[wi] = bp;
                u64 st = bt & ~((bt << 1) | carryT);
                sT[wi] = st; prT[wi] = cumT;
                cumT += (int)__popcll(st); carryT = bt >> 63;
                u64 sq = bp & ~((bp << 1) | carryP);
                sP[wi] = sq; prP[wi] = cumP;
                cumP += (int)__popcll(sq); carryP = bp >> 63;
            }
        }
        if (lane == 0) { rcT[R] = cumT; rcP[R] = cumP; }
    }
    lsum *= 0.5;
    #pragma unroll
    for (int off = 32; off > 0; off >>= 1) lsum += __shfl_down(lsum, off, 64);
    __shared__ double sh[4];
    if (lane == 0) sh[wid] = lsum;
    __syncthreads();
    if (threadIdx.x == 0) part[blockIdx.x] += sh[0] + sh[1] + sh[2] + sh[3];
}

// One block per (image, strip, phase): intra-strip CCL + flags in 32KB LDS.
__global__ __launch_bounds__(NTHR_S) void
k_strip(const u64* __restrict__ fT, const u64* __restrict__ fP,
        const u64* __restrict__ sT, const u64* __restrict__ sP,
        const int* __restrict__ prT, const int* __restrict__ prP,
        const int* __restrict__ rcT, const int* __restrict__ rcP,
        int* __restrict__ parentT, int* __restrict__ parentP) {
    __shared__ int lab[SLOTS];
    __shared__ int rcL[SROWS];
    int bid = blockIdx.x;
    int ph = bid & 1; bid >>= 1;
    int strip = bid & (STRIPS - 1);
    int img = bid >> 6;  // STRIPS = 64
    const u64* f = ph ? fP : fT;
    const u64* fB = ph ? fT : fP;
    const u64* s = ph ? sP : sT;
    const int* pr = ph ? prP : prT;
    const int* rc = ph ? rcP : rcT;
    int* parent = ph ? parentP : parentT;
    const int row0 = img * HH + strip * SROWS;

    if (threadIdx.x < SROWS) rcL[threadIdx.x] = rc[row0 + threadIdx.x];
    __syncthreads();

    // init used slots only (unused are never read)
    for (int i = threadIdx.x; i < SLOTS; i += NTHR_S)
        if ((i & (RPR - 1)) < rcL[i >> 9]) lab[i] = i;
    __syncthreads();

    // intra-strip vertical unites, 4-way sub-word split
    for (int task = threadIdx.x; task < (SROWS - 1) * WPR * 4; task += NTHR_S) {
        int j = task & 3, w = (task >> 2) & 15, r = task >> 6;
        int w0 = (row0 + r) * WPR + w, w1 = w0 + WPR;
        u64 o = f[w0] & f[w1];
        if (!o) continue;
        u64 s0 = s[w0], s1 = s[w1];
        int b0 = r * RPR + pr[w0], b1 = (r + 1) * RPR + pr[w1];
        u64 os = o & ~(o << 1);
        int k = 0;
        while (os) {
            int b = __builtin_ctzll(os);
            os &= os - 1;
            if ((k++ & 3) == j)
                uniteL(lab, b0 + runIndexW(s0, b), b1 + runIndexW(s1, b));
        }
    }
    __syncthreads();

    // mistake flags onto local roots, 4-way sub-word split
    volatile int* vl = lab;
    for (int task = threadIdx.x; task < SROWS * WPR * 4; task += NTHR_S) {
        int j = task & 3, w = (task >> 2) & 15, r = task >> 6;
        int wi = (row0 + r) * WPR + w;
        u64 m = f[wi] & ~fB[wi];
        if (!m) continue;
        u64 sw = s[wi];
        int base = r * RPR + pr[wi];
        u64 ms = m & ~(m << 1);
        int k = 0, last = -1;
        while (ms) {
            int b = __builtin_ctzll(ms);
            ms &= ms - 1;
            if ((k++ & 3) != j) continue;
            int rid = base + runIndexW(sw, b);
            if (rid == last) continue;
            last = rid;
            int rt = findRootL(vl, rid);
            if (!(vl[rt] & FLAGBIT)) atomicOr(&lab[rt], FLAGBIT);
        }
    }
    __syncthreads();

    // compress + write used slots (root entries carry flag)
    const int gb = row0 * RPR;
    for (int i = threadIdx.x; i < SLOTS; i += NTHR_S) {
        if ((i & (RPR - 1)) >= rcL[i >> 9]) continue;
        int e = lab[i];
        int rt = e & IDXMASK;
        if (rt != i) rt = findRootL(vl, rt);
        parent[gb + i] = (rt == i) ? ((gb + i) | (e & FLAGBIT)) : (gb + rt);
    }
}

// Global flag-carrying unions across the 63 strip seams per image, 4-way split.
__global__ void k_bound(const u64* __restrict__ fT, const u64* __restrict__ fP,
                        const u64* __restrict__ sT, const u64* __restrict__ sP,
                        const int* __restrict__ prT, const int* __restrict__ prP,
                        int* __restrict__ parentT, int* __restrict__ parentP, int nb) {
    int tasks = nb * (STRIPS - 1) * WPR * 2 * 4;
    int stride = gridDim.x * blockDim.x;
    for (int id = blockIdx.x * blockDim.x + threadIdx.x; id < tasks; id += stride) {
        int j = id & 3;
        int t = id >> 2;
        int ph = t & 1; t >>= 1;
        int w = t & 15; t >>= 4;
        int bnd = t % (STRIPS - 1);
        int img = t / (STRIPS - 1);
        int R = img * HH + bnd * SROWS + (SROWS - 1);  // last row of strip bnd
        const u64* f = ph ? fP : fT;
        const u64* s = ph ? sP : sT;
        const int* pr = ph ? prP : prT;
        int* parent = ph ? parentP : parentT;
        int w0 = R * WPR + w, w1 = w0 + WPR;
        u64 o = f[w0] & f[w1];
        if (!o) continue;
        u64 s0 = s[w0], s1 = s[w1];
        int b0 = R * RPR + pr[w0], b1 = (R + 1) * RPR + pr[w1];
        u64 os = o & ~(o << 1);
        int k = 0;
        while (os) {
            int b = __builtin_ctzll(os);
            os &= os - 1;
            if ((k++ & 3) == j)
                uniteGF(parent, b0 + runIndexW(s0, b), b1 + runIndexW(s1, b));
        }
    }
}

// Used-slots-only: every entry -> finalroot | rootflag.
__global__ void k_compress(const int* __restrict__ rcT, const int* __restrict__ rcP,
                           int* __restrict__ parentT, int* __restrict__ parentP, int nruns) {
    int stride = gridDim.x * blockDim.x;
    for (int i = blockIdx.x * blockDim.x + threadIdx.x; i < nruns; i += stride) {
        int row = i >> 9, idx = i & (RPR - 1);
        if (idx < rcT[row]) {
            int e = parentT[i];
            int r = e & IDXMASK;
            int fl;
            if (r == i) fl = e & FLAGBIT;
            else { r = findRootG(parentT, r); fl = parentT[r] & FLAGBIT; }
            parentT[i] = r | fl;
        }
        if (idx < rcP[row]) {
            int e = parentP[i];
            int r = e & IDXMASK;
            int fl;
            if (r == i) fl = e & FLAGBIT;
            else { r = findRootG(parentP, r); fl = parentP[r] & FLAGBIT; }
            parentP[i] = r | fl;
        }
    }
}

// Adds 0.25*loss for fg pixels of flagged components (both phases).
__global__ void k_accumflag(const _Float16* __restrict__ lossH, int npx4,
                            const u64* __restrict__ fT, const u64* __restrict__ fP,
                            const u64* __restrict__ sT, const u64* __restrict__ sP,
                            const int* __restrict__ prT, const int* __restrict__ prP,
                            const int* __restrict__ parentT, const int* __restrict__ parentP,
                            double* __restrict__ part) {
    int stride = gridDim.x * blockDim.x;
    double local = 0.0;
    const ushort4* lh4 = (const ushort4*)lossH;
    for (int i = blockIdx.x * blockDim.x + threadIdx.x; i < npx4; i += stride) {
        int px = i << 2;
        int R = px >> 10;
        int wi = R * WPR + ((px >> 6) & 15);
        u64 ft = fT[wi], fp = fP[wi];
        int b0 = px & 63;
        u64 mask4 = 0xFULL << b0;
        bool anyT = (ft & mask4) != 0, anyP = (fp & mask4) != 0;
        if (!anyT && !anyP) continue;
        ushort4 lw = lh4[i];
        u64 st = 0, sq = 0;
        int baseT = 0, baseP = 0;
        if (anyT) { st = sT[wi]; baseT = R * RPR + prT[wi]; }
        if (anyP) { sq = sP[wi]; baseP = R * RPR + prP[wi]; }
        unsigned short la[4] = {lw.x, lw.y, lw.z, lw.w};
        int lastT = -1, lastP = -1;
        float flagT = 0.0f, flagP = 0.0f;
        #pragma unroll
        for (int jj = 0; jj < 4; ++jj) {
            int b = b0 + jj;
            bool ftb = (ft >> b) & 1, fpb = (fp >> b) & 1;
            if (!(ftb || fpb)) continue;
            union { unsigned short u; _Float16 h; } cv;
            cv.u = la[jj];
            float loss = (float)cv.h;
            float c = 0.0f;
            if (ftb) {
                int rid = baseT + runIndexW(st, b);
                if (rid != lastT) { lastT = rid; flagT = (parentT[rid] & FLAGBIT) ? 0.25f : 0.0f; }
                c += flagT;
            }
            if (fpb) {
                int rid = baseP + runIndexW(sq, b);
                if (rid != lastP) { lastP = rid; flagP = (parentP[rid] & FLAGBIT) ? 0.25f : 0.0f; }
                c += flagP;
            }
            local += (double)(c * loss);
        }
    }
    #pragma unroll
    for (int off = 32; off > 0; off >>= 1) local += __shfl_down(local, off, 64);
    __shared__ double sh[NTHR / 64];
    int lane = threadIdx.x & 63, wid = threadIdx.x >> 6;
    if (lane == 0) sh[wid] = local;
    __syncthreads();
    if (threadIdx.x == 0) {
        double tot = 0.0;
        #pragma unroll
        for (int w = 0; w < NTHR / 64; ++w) tot += sh[w];
        part[blockIdx.x] += tot;
    }
}

__global__ void k_final(const double* __restrict__ part, float* __restrict__ out, double inv_n) {
    double v = 0.0;
    for (int i = threadIdx.x; i < NPART; i += blockDim.x) v += part[i];
    #pragma unroll
    for (int off = 32; off > 0; off >>= 1) v += __shfl_down(v, off, 64);
    __shared__ double sh[NTHR / 64];
    int lane = threadIdx.x & 63, wid = threadIdx.x >> 6;
    if (lane == 0) sh[wid] = v;
    __syncthreads();
    if (threadIdx.x == 0) {
        double tot = 0.0;
        #pragma unroll
        for (int w = 0; w < NTHR / 64; ++w) tot += sh[w];
        out[0] = (float)(tot * inv_n);
    }
}

extern "C" void kernel_launch(void* const* d_in, const int* in_sizes, int n_in,
                              void* d_out, int out_size, void* d_ws, size_t ws_size,
                              hipStream_t stream) {
    const float* preds = (const float*)d_in[0];
    const float* targets = (const float*)d_in[1];
    float* out = (float*)d_out;

    // ws: part | fT fP sT sP (u64) | prT prP rcT rcP parentT parentP (int) | lossH
    double* part = (double*)d_ws;
    char* base = (char*)d_ws + NPART * sizeof(double);
    size_t avail = (ws_size > NPART * sizeof(double)) ? ws_size - NPART * sizeof(double) : 0;
    const size_t wpi = (size_t)HH * WPR;       // 16384 words per image
    const size_t runs_pi = (size_t)HH * RPR;   // 524288 run slots per image
    const size_t per_img = 4 * wpi * sizeof(u64) + 2 * wpi * sizeof(int)
                         + 2 * HH * sizeof(int) + 2 * runs_pi * sizeof(int)
                         + (size_t)IMGPIX * 2;  // ~6.6 MB
    int chunk = (int)(avail / per_img);
    if (chunk < 1) chunk = 1;
    if (chunk > NB_TOTAL) chunk = NB_TOTAL;

    u64* fT = (u64*)base;
    u64* fP = fT + (size_t)chunk * wpi;
    u64* sT = fP + (size_t)chunk * wpi;
    u64* sP = sT + (size_t)chunk * wpi;
    int* prT = (int*)(sP + (size_t)chunk * wpi);
    int* prP = prT + (size_t)chunk * wpi;
    int* rcT = prP + (size_t)chunk * wpi;
    int* rcP = rcT + (size_t)chunk * HH;
    int* parentT = rcP + (size_t)chunk * HH;
    int* parentP = parentT + (size_t)chunk * runs_pi;
    _Float16* lossH = (_Float16*)(parentP + (size_t)chunk * runs_pi);

    k_zero<<<NPART / NTHR, NTHR, 0, stream>>>(part);

    for (int b0 = 0; b0 < NB_TOTAL; b0 += chunk) {
        int nb = (b0 + chunk <= NB_TOTAL) ? chunk : (NB_TOTAL - b0);
        int npx = nb * IMGPIX;
        long gbase = (long)b0 * IMGPIX;
        int nrows = nb * HH;
        int nruns = (int)(nb * runs_pi);

        k_maskloss<<<NBLK, NTHR, 0, stream>>>(preds, targets, gbase, nrows,
                                              fT, fP, sT, sP, prT, prP, rcT, rcP,
                                              lossH, part);
        k_strip<<<nb * STRIPS * 2, NTHR_S, 0, stream>>>(fT, fP, sT, sP, prT, prP,
                                                        rcT, rcP, parentT, parentP);
        k_bound<<<512, NTHR, 0, stream>>>(fT, fP, sT, sP, prT, prP, parentT, parentP, nb);
        k_compress<<<NBLK, NTHR, 0, stream>>>(rcT, rcP, parentT, parentP, nruns);
        k_accumflag<<<NBLK, NTHR, 0, stream>>>(lossH, npx >> 2, fT, fP, sT, sP,
                                               prT, prP, parentT, parentP, part);
    }

    double inv_n = 1.0 / ((double)NB_TOTAL * (double)IMGPIX);
    k_final<<<1, NTHR, 0, stream>>>(part, out, inv_n);
}

// Round 9
// 279.018 us; speedup vs baseline: 1.2760x; 1.2760x over previous
//
#include <hip/hip_runtime.h>
#include <math.h>

// SuperVoxel critical-component loss on MI355X.
// mean( (0.5 + 0.25*neg + 0.25*pos) * bce_loss )
// Run-based two-level CCL with path-halving union-find.
//  k_maskloss: read floats ONCE -> fg masks, run starts/prefixes/counts (lane-
//              parallel + shfl scan), fp16 loss, 0.5*sum(loss) base term.
//  k_strip:    32-row strips, intra-strip unions+flags in 64KB LDS,
//              used-slots-only, path-halving finds.
//  k_bound:    global flag-carrying unions on 31 strip seams per image.
//  k_flagfold: per-run flag BITMASK (64KB/img/phase) from root flags.
//  k_accumflag: adds 0.25*loss for runs whose flag bit is set.

#define HH 1024
#define WW 1024
#define IMGPIX (HH * WW)
#define NB_TOTAL 16
#define FLAGBIT 0x40000000
#define IDXMASK 0x3FFFFFFF
#define NBLK 2048
#define NPART 2048
#define NTHR 256
#define WPR 16               // u64 mask words per row
#define RPR 512              // run slots per row (hard worst case)
#define SROWS 32             // rows per strip
#define STRIPS (HH / SROWS)  // 32 strips per image
#define SLOTS (SROWS * RPR)  // 16384 slots per strip (64KB LDS)
#define NTHR_S 1024

typedef unsigned long long u64;

// ---------- global union-find, path-halving, flag-aware ----------
__device__ __forceinline__ int findRootH(int* p, int i) {
    volatile int* vp = p;
    int r = i;
    int e = vp[r] & IDXMASK;
    while (e != r) {
        int e2 = vp[e] & IDXMASK;
        if (e2 != e) p[r] = e2;  // shortcut: only non-roots written (no flags there)
        r = e; e = e2;
    }
    return r;
}

__device__ __forceinline__ void flagProp(int* p, int x) {
    while (true) {
        int r = findRootH(p, x);
        int old = atomicOr(&p[r], FLAGBIT);
        if ((old & IDXMASK) == r) return;  // was still a root
        x = old & IDXMASK;
    }
}

__device__ __forceinline__ void uniteGF(int* p, int a, int b) {
    int ra = findRootH(p, a), rb = findRootH(p, b);
    while (ra != rb) {
        if (ra < rb) { int t = ra; ra = rb; rb = t; }  // hook larger under smaller
        int e = p[ra];
        if ((e & IDXMASK) != ra) { ra = findRootH(p, e & IDXMASK); continue; }
        int prev = atomicCAS(&p[ra], e, rb);
        if (prev == e) {
            if (e & FLAGBIT) flagProp(p, rb);
            return;
        }
        ra = findRootH(p, prev & IDXMASK);
        rb = findRootH(p, rb);
    }
}

// ---------- LDS union-find, path-halving ----------
__device__ __forceinline__ int findRootL(int* lab, int i) {
    volatile int* vl = lab;
    int r = i;
    int e = vl[r] & IDXMASK;
    while (e != r) {
        int e2 = vl[e] & IDXMASK;
        if (e2 != e) lab[r] = e2;
        r = e; e = e2;
    }
    return r;
}

__device__ __forceinline__ void uniteL(int* lab, int a, int b) {
    int ra = findRootL(lab, a), rb = findRootL(lab, b);
    while (ra != rb) {
        if (ra < rb) { int t = ra; ra = rb; rb = t; }
        int prev = atomicCAS(&lab[ra], ra, rb);
        if (prev == ra) return;
        ra = findRootL(lab, prev & IDXMASK);
        rb = findRootL(lab, rb);
    }
}

// index (within row) of the run containing bit b of this word; requires fg@b.
__device__ __forceinline__ int runIndexW(u64 starts, int b) {
    u64 below = (2ULL << b) - 1ULL;  // b=63 wraps to ~0ULL
    return (int)__popcll(starts & below) - 1;
}

__global__ void k_zero(double* __restrict__ part) {
    part[blockIdx.x * blockDim.x + threadIdx.x] = 0.0;
}

// Wave-per-row: read floats once; lane-parallel mask/run postprocessing.
__global__ void k_maskloss(const float* __restrict__ preds, const float* __restrict__ targets,
                           long gbase, int nrows,
                           u64* __restrict__ fT, u64* __restrict__ fP,
                           u64* __restrict__ sT, u64* __restrict__ sP,
                           int* __restrict__ prT, int* __restrict__ prP,
                           int* __restrict__ rcT, int* __restrict__ rcP,
                           _Float16* __restrict__ lossH, double* __restrict__ part) {
    int wid = threadIdx.x >> 6, lane = threadIdx.x & 63;
    double lsum = 0.0;
    for (int R = blockIdx.x * 4 + wid; R < nrows; R += gridDim.x * 4) {
        long pixbase = (long)R * WW;
        u64 myW = 0;  // lanes 0..15: T word[lane]; lanes 16..31: P word[lane-16]
        #pragma unroll 4
        for (int w = 0; w < WPR; ++w) {
            long g = gbase + pixbase + w * 64 + lane;
            float p = preds[g], t = targets[g];
            float loss = fmaxf(p, 0.0f) - p * t + __logf(1.0f + __expf(-fabsf(p)));
            lossH[pixbase + w * 64 + lane] = (_Float16)loss;
            lsum += (double)loss;
            u64 bt = __ballot(t > 0.0f);
            u64 bp = __ballot(p > 0.5f);
            if (lane == w) myW = bt;
            if (lane == w + 16) myW = bp;
        }
        if (lane < 32) {
            int subid = lane & 15;
            u64 prevW = __shfl_up(myW, 1, 16);
            u64 carry = (subid > 0) ? (prevW >> 63) : 0ULL;
            u64 st = myW & ~((myW << 1) | carry);
            int cnt = (int)__popcll(st);
            int incl = cnt;
            #pragma unroll
            for (int d = 1; d < 16; d <<= 1) {
                int v = __shfl_up(incl, d, 16);
                if (subid >= d) incl += v;
            }
            int excl = incl - cnt;
            int wi = R * WPR + subid;
            if (lane < 16) {
                fT[wi] = myW; sT[wi] = st; prT[wi] = excl;
                if (subid == 15) rcT[R] = incl;
            } else {
                fP[wi] = myW; sP[wi] = st; prP[wi] = excl;
                if (subid == 15) rcP[R] = incl;
            }
        }
    }
    lsum *= 0.5;
    #pragma unroll
    for (int off = 32; off > 0; off >>= 1) lsum += __shfl_down(lsum, off, 64);
    __shared__ double sh[4];
    if (lane == 0) sh[wid] = lsum;
    __syncthreads();
    if (threadIdx.x == 0) part[blockIdx.x] += sh[0] + sh[1] + sh[2] + sh[3];
}

// One block per (image, strip, phase): intra-strip CCL + flags in 64KB LDS.
__global__ __launch_bounds__(NTHR_S) void
k_strip(const u64* __restrict__ fT, const u64* __restrict__ fP,
        const u64* __restrict__ sT, const u64* __restrict__ sP,
        const int* __restrict__ prT, const int* __restrict__ prP,
        const int* __restrict__ rcT, const int* __restrict__ rcP,
        int* __restrict__ parentT, int* __restrict__ parentP) {
    __shared__ int lab[SLOTS];
    __shared__ int rcL[SROWS];
    int bid = blockIdx.x;
    int ph = bid & 1; bid >>= 1;
    int strip = bid & (STRIPS - 1);
    int img = bid >> 5;  // STRIPS = 32
    const u64* f = ph ? fP : fT;
    const u64* fB = ph ? fT : fP;
    const u64* s = ph ? sP : sT;
    const int* pr = ph ? prP : prT;
    const int* rc = ph ? rcP : rcT;
    int* parent = ph ? parentP : parentT;
    const int row0 = img * HH + strip * SROWS;

    if (threadIdx.x < SROWS) rcL[threadIdx.x] = rc[row0 + threadIdx.x];
    __syncthreads();

    // init used slots only
    for (int i = threadIdx.x; i < SLOTS; i += NTHR_S)
        if ((i & (RPR - 1)) < rcL[i >> 9]) lab[i] = i;
    __syncthreads();

    // intra-strip vertical unites, 2-way sub-word split
    for (int task = threadIdx.x; task < (SROWS - 1) * WPR * 2; task += NTHR_S) {
        int j = task & 1, w = (task >> 1) & 15, r = task >> 5;
        int w0 = (row0 + r) * WPR + w, w1 = w0 + WPR;
        u64 o = f[w0] & f[w1];
        if (!o) continue;
        u64 s0 = s[w0], s1 = s[w1];
        int b0 = r * RPR + pr[w0], b1 = (r + 1) * RPR + pr[w1];
        u64 os = o & ~(o << 1);
        int k = 0;
        while (os) {
            int b = __builtin_ctzll(os);
            os &= os - 1;
            if ((k++ & 1) == j)
                uniteL(lab, b0 + runIndexW(s0, b), b1 + runIndexW(s1, b));
        }
    }
    __syncthreads();

    // mistake flags onto local roots, 2-way sub-word split
    for (int task = threadIdx.x; task < SROWS * WPR * 2; task += NTHR_S) {
        int j = task & 1, w = (task >> 1) & 15, r = task >> 5;
        int wi = (row0 + r) * WPR + w;
        u64 m = f[wi] & ~fB[wi];
        if (!m) continue;
        u64 sw = s[wi];
        int base = r * RPR + pr[wi];
        u64 ms = m & ~(m << 1);
        int k = 0, last = -1;
        while (ms) {
            int b = __builtin_ctzll(ms);
            ms &= ms - 1;
            if ((k++ & 1) != j) continue;
            int rid = base + runIndexW(sw, b);
            if (rid == last) continue;
            last = rid;
            int rt = findRootL(lab, rid);
            if (!(((volatile int*)lab)[rt] & FLAGBIT)) atomicOr(&lab[rt], FLAGBIT);
        }
    }
    __syncthreads();

    // compress + write used slots (root entries carry flag)
    const int gb = row0 * RPR;
    for (int i = threadIdx.x; i < SLOTS; i += NTHR_S) {
        if ((i & (RPR - 1)) >= rcL[i >> 9]) continue;
        int e = lab[i];
        int rt = e & IDXMASK;
        if (rt != i) rt = findRootL(lab, rt);
        parent[gb + i] = (rt == i) ? ((gb + i) | (e & FLAGBIT)) : (gb + rt);
    }
}

// Global flag-carrying unions across the 31 strip seams per image.
__global__ void k_bound(const u64* __restrict__ fT, const u64* __restrict__ fP,
                        const u64* __restrict__ sT, const u64* __restrict__ sP,
                        const int* __restrict__ prT, const int* __restrict__ prP,
                        int* __restrict__ parentT, int* __restrict__ parentP, int nb) {
    int tasks = nb * (STRIPS - 1) * WPR * 2;
    int stride = gridDim.x * blockDim.x;
    for (int id = blockIdx.x * blockDim.x + threadIdx.x; id < tasks; id += stride) {
        int ph = id & 1;
        int t = id >> 1;
        int w = t & 15; t >>= 4;
        int bnd = t % (STRIPS - 1);
        int img = t / (STRIPS - 1);
        int R = img * HH + bnd * SROWS + (SROWS - 1);  // last row of strip bnd
        const u64* f = ph ? fP : fT;
        const u64* s = ph ? sP : sT;
        const int* pr = ph ? prP : prT;
        int* parent = ph ? parentP : parentT;
        int w0 = R * WPR + w, w1 = w0 + WPR;
        u64 o = f[w0] & f[w1];
        if (!o) continue;
        u64 s0 = s[w0], s1 = s[w1];
        int b0 = R * RPR + pr[w0], b1 = (R + 1) * RPR + pr[w1];
        u64 os = o & ~(o << 1);
        while (os) {
            int b = __builtin_ctzll(os);
            os &= os - 1;
            uniteGF(parent, b0 + runIndexW(s0, b), b1 + runIndexW(s1, b));
        }
    }
}

// Per-run flag bitmask: one thread per 64-slot flag word, used slots only.
__global__ void k_flagfold(const int* __restrict__ rcT, const int* __restrict__ rcP,
                           int* __restrict__ parentT, int* __restrict__ parentP,
                           u64* __restrict__ flagT, u64* __restrict__ flagP, int nfw) {
    int stride = gridDim.x * blockDim.x;
    for (int id = blockIdx.x * blockDim.x + threadIdx.x; id < 2 * nfw; id += stride) {
        int ph = id >= nfw;
        int fw = ph ? id - nfw : id;
        int row = fw >> 3, k = fw & 7;  // 8 flag words per 512-slot row
        const int* rc = ph ? rcP : rcT;
        int* parent = ph ? parentP : parentT;
        u64* flags = ph ? flagP : flagT;
        int cnt = rc[row];
        int s0 = k * 64;
        int s1 = min(s0 + 64, cnt);
        u64 bits = 0;
        int base = row * RPR;
        for (int sidx = s0; sidx < s1; ++sidx) {
            int i = base + sidx;
            int e = parent[i];
            int r = e & IDXMASK;
            int fl;
            if (r == i) fl = e & FLAGBIT;
            else { r = findRootH(parent, r); fl = parent[r] & FLAGBIT; }
            if (fl) bits |= 1ULL << (sidx - s0);
        }
        flags[fw] = bits;
    }
}

// Adds 0.25*loss for fg pixels whose run's flag bit is set (both phases).
__global__ void k_accumflag(const _Float16* __restrict__ lossH, int npx4,
                            const u64* __restrict__ fT, const u64* __restrict__ fP,
                            const u64* __restrict__ sT, const u64* __restrict__ sP,
                            const int* __restrict__ prT, const int* __restrict__ prP,
                            const u64* __restrict__ flagT, const u64* __restrict__ flagP,
                            double* __restrict__ part) {
    int stride = gridDim.x * blockDim.x;
    double local = 0.0;
    const ushort4* lh4 = (const ushort4*)lossH;
    for (int i = blockIdx.x * blockDim.x + threadIdx.x; i < npx4; i += stride) {
        int px = i << 2;
        int R = px >> 10;
        int wi = R * WPR + ((px >> 6) & 15);
        u64 ft = fT[wi], fp = fP[wi];
        int b0 = px & 63;
        u64 mask4 = 0xFULL << b0;
        bool anyT = (ft & mask4) != 0, anyP = (fp & mask4) != 0;
        if (!anyT && !anyP) continue;
        ushort4 lw = lh4[i];
        u64 st = 0, sq = 0;
        int baseT = 0, baseP = 0;
        if (anyT) { st = sT[wi]; baseT = R * RPR + prT[wi]; }
        if (anyP) { sq = sP[wi]; baseP = R * RPR + prP[wi]; }
        unsigned short la[4] = {lw.x, lw.y, lw.z, lw.w};
        int lastT = -1, lastP = -1;
        float flagTv = 0.0f, flagPv = 0.0f;
        #pragma unroll
        for (int jj = 0; jj < 4; ++jj) {
            int b = b0 + jj;
            bool ftb = (ft >> b) & 1, fpb = (fp >> b) & 1;
            if (!(ftb || fpb)) continue;
            union { unsigned short u; _Float16 h; } cv;
            cv.u = la[jj];
            float loss = (float)cv.h;
            float c = 0.0f;
            if (ftb) {
                int rid = baseT + runIndexW(st, b);
                if (rid != lastT) {
                    lastT = rid;
                    flagTv = ((flagT[rid >> 6] >> (rid & 63)) & 1) ? 0.25f : 0.0f;
                }
                c += flagTv;
            }
            if (fpb) {
                int rid = baseP + runIndexW(sq, b);
                if (rid != lastP) {
                    lastP = rid;
                    flagPv = ((flagP[rid >> 6] >> (rid & 63)) & 1) ? 0.25f : 0.0f;
                }
                c += flagPv;
            }
            local += (double)(c * loss);
        }
    }
    #pragma unroll
    for (int off = 32; off > 0; off >>= 1) local += __shfl_down(local, off, 64);
    __shared__ double sh[NTHR / 64];
    int lane = threadIdx.x & 63, wid = threadIdx.x >> 6;
    if (lane == 0) sh[wid] = local;
    __syncthreads();
    if (threadIdx.x == 0) {
        double tot = 0.0;
        #pragma unroll
        for (int w = 0; w < NTHR / 64; ++w) tot += sh[w];
        part[blockIdx.x] += tot;
    }
}

__global__ void k_final(const double* __restrict__ part, float* __restrict__ out, double inv_n) {
    double v = 0.0;
    for (int i = threadIdx.x; i < NPART; i += blockDim.x) v += part[i];
    #pragma unroll
    for (int off = 32; off > 0; off >>= 1) v += __shfl_down(v, off, 64);
    __shared__ double sh[NTHR / 64];
    int lane = threadIdx.x & 63, wid = threadIdx.x >> 6;
    if (lane == 0) sh[wid] = v;
    __syncthreads();
    if (threadIdx.x == 0) {
        double tot = 0.0;
        #pragma unroll
        for (int w = 0; w < NTHR / 64; ++w) tot += sh[w];
        out[0] = (float)(tot * inv_n);
    }
}

extern "C" void kernel_launch(void* const* d_in, const int* in_sizes, int n_in,
                              void* d_out, int out_size, void* d_ws, size_t ws_size,
                              hipStream_t stream) {
    const float* preds = (const float*)d_in[0];
    const float* targets = (const float*)d_in[1];
    float* out = (float*)d_out;

    // ws: part | fT fP sT sP (u64) | prT prP rcT rcP parentT parentP (int)
    //    | flagT flagP (u64) | lossH (fp16)       (chunked by image)
    double* part = (double*)d_ws;
    char* base = (char*)d_ws + NPART * sizeof(double);
    size_t avail = (ws_size > NPART * sizeof(double)) ? ws_size - NPART * sizeof(double) : 0;
    const size_t wpi = (size_t)HH * WPR;       // 16384 words per image
    const size_t runs_pi = (size_t)HH * RPR;   // 524288 run slots per image
    const size_t fw_pi = runs_pi / 64;         // 8192 flag words per image
    const size_t per_img = 4 * wpi * sizeof(u64) + 2 * wpi * sizeof(int)
                         + 2 * HH * sizeof(int) + 2 * runs_pi * sizeof(int)
                         + 2 * fw_pi * sizeof(u64) + (size_t)IMGPIX * 2;  // ~7.1 MB
    int chunk = (int)(avail / per_img);
    if (chunk < 1) chunk = 1;
    if (chunk > NB_TOTAL) chunk = NB_TOTAL;

    u64* fT = (u64*)base;
    u64* fP = fT + (size_t)chunk * wpi;
    u64* sT = fP + (size_t)chunk * wpi;
    u64* sP = sT + (size_t)chunk * wpi;
    int* prT = (int*)(sP + (size_t)chunk * wpi);
    int* prP = prT + (size_t)chunk * wpi;
    int* rcT = prP + (size_t)chunk * wpi;
    int* rcP = rcT + (size_t)chunk * HH;
    int* parentT = rcP + (size_t)chunk * HH;
    int* parentP = parentT + (size_t)chunk * runs_pi;
    u64* flagT = (u64*)(parentP + (size_t)chunk * runs_pi);
    u64* flagP = flagT + (size_t)chunk * fw_pi;
    _Float16* lossH = (_Float16*)(flagP + (size_t)chunk * fw_pi);

    k_zero<<<NPART / NTHR, NTHR, 0, stream>>>(part);

    for (int b0 = 0; b0 < NB_TOTAL; b0 += chunk) {
        int nb = (b0 + chunk <= NB_TOTAL) ? chunk : (NB_TOTAL - b0);
        int npx = nb * IMGPIX;
        long gbase = (long)b0 * IMGPIX;
        int nrows = nb * HH;
        int nfw = (int)(nb * fw_pi);

        k_maskloss<<<NBLK, NTHR, 0, stream>>>(preds, targets, gbase, nrows,
                                              fT, fP, sT, sP, prT, prP, rcT, rcP,
                                              lossH, part);
        k_strip<<<nb * STRIPS * 2, NTHR_S, 0, stream>>>(fT, fP, sT, sP, prT, prP,
                                                        rcT, rcP, parentT, parentP);
        k_bound<<<128, NTHR, 0, stream>>>(fT, fP, sT, sP, prT, prP, parentT, parentP, nb);
        k_flagfold<<<1024, NTHR, 0, stream>>>(rcT, rcP, parentT, parentP, flagT, flagP, nfw);
        k_accumflag<<<NBLK, NTHR, 0, stream>>>(lossH, npx >> 2, fT, fP, sT, sP,
                                               prT, prP, flagT, flagP, part);
    }

    double inv_n = 1.0 / ((double)NB_TOTAL * (double)IMGPIX);
    k_final<<<1, NTHR, 0, stream>>>(part, out, inv_n);
}